// Round 17
// baseline (120.482 us; speedup 1.0000x reference)
//
#include <hip/hip_runtime.h>
#include <math.h>

#define NB 4
#define HID 4096
#define CKV 512
#define CQ 1536
#define NH 32
#define HD 128
#define RD 64
#define SS 4096
#define SK 4097
#define SKP 4100

#define SCALE_F 0.07216878364870322f  // 1/sqrt(192)

#define NP1 64   // proj1 k-partials
#define NP2 24   // proj2 k-partials
#define NPV 32   // attn key-chunks (128 keys; chunk 31 also holds key 4096)
#define NUV 16   // uv c-partials
#define NWO 32   // wo k-partials

#define KD   576      // latent 512 + rope 64, contiguous bf16 rows
#define QKB_STR 584   // kv LDS bf16 row stride
#define PBF_STR 4104  // (legacy, unused)
#define TV_STR 40     // kvT LDS row stride in u16
#define SFS  168      // S_s row stride (f32)
#define PSTR 168      // P_s row stride (bf16; 336 B, 16B-aligned)

typedef __attribute__((ext_vector_type(8))) short short8v;
typedef __attribute__((ext_vector_type(4))) float f32x4;

// workspace offsets (floats). ALL regions disjoint (ws is 256 MB).
enum : int {
  WS_QABS  = 0,
  WS_QROPE = WS_QABS + NB*NH*CKV,
  WS_KROPE = WS_QROPE + NB*NH*RD,
  WS_CKV   = WS_KROPE + NB*RD,
  WS_CQ    = WS_CKV + NB*CKV,
  WS_SCA   = WS_CQ + NB*CQ,            // (legacy, unused)
  WS_P1    = WS_SCA + NB*NH*SKP,
  WS_P2    = WS_P1 + NP1*NB*528*4,
  WS_OPART = WS_P2 + NP2*NB*6144,      // [NPV][NB][NH][CKV]
  WS_UVPART= WS_OPART + NPV*NB*NH*CKV,
  WS_WOPART= WS_UVPART + NUV*NB*HID,
  WS_KVBF  = WS_WOPART + NWO*NB*HID,   // bf16 [NB][SK][576]
  WS_QBF   = WS_KVBF + (NB*SK*KD)/2,   // bf16 [NB][NH][576]
  WS_ML    = WS_QBF + (NB*NH*KD)/2,    // [NB][NH][NPV][2] (m_j, l_j)
  WS_TOTAL = WS_ML + NB*NH*NPV*2
};

__device__ inline void fma4(float4& a, float s, const float4& v) {
  a.x += s*v.x; a.y += s*v.y; a.z += s*v.z; a.w += s*v.w;
}
__device__ inline float dot4(const float4& a, const float4& b) {
  return a.x*b.x + a.y*b.y + a.z*b.z + a.w*b.w;
}
__device__ inline unsigned short f2bf(float f) {
  union { float f; unsigned int u; } v; v.f = f;
  unsigned int r = v.u + 0x7FFFu + ((v.u >> 16) & 1u);
  return (unsigned short)(r >> 16);
}
__device__ inline ushort4 f2bf4(float4 v) {
  ushort4 r; r.x = f2bf(v.x); r.y = f2bf(v.y); r.z = f2bf(v.z); r.w = f2bf(v.w);
  return r;
}
__device__ inline float bf2f(unsigned short u) {
  union { unsigned int u; float f; } v; v.u = ((unsigned int)u) << 16;
  return v.f;
}

// ------- L1: [bx<576] proj1 -> P1 partials | [else] cache copy + bf16 copy --
__global__ __launch_bounds__(256)
void k_proj1copy(const float* __restrict__ hidden,
                 const float* __restrict__ Wdkv,
                 const float* __restrict__ Wdq,
                 const float* __restrict__ Wkr,
                 float* __restrict__ ws,
                 const float4* __restrict__ src_ckv,
                 const float4* __restrict__ src_kr,
                 float4* __restrict__ dst_ckv,
                 float4* __restrict__ dst_kr) {
  __shared__ float4 red_s[4][NB][64];
  unsigned short* kvbf = (unsigned short*)(ws + WS_KVBF);
  const int bx = blockIdx.x;
  if (bx < 576) {
    const int gx = bx % 9, gy = bx / 9;
    const int lane = threadIdx.x & 63, ksub = threadIdx.x >> 6;
    const int col4 = gx * 64 + lane;
    const int k0 = gy * 64 + ksub * 16;
    const bool valid = col4 < 528;
    float4 acc[NB] = {};
    if (valid) {
      const float* W; int C4, wcol4;
      if (col4 < 128)      { W = Wdkv; C4 = 128; wcol4 = col4; }
      else if (col4 < 512) { W = Wdq;  C4 = 384; wcol4 = col4 - 128; }
      else                 { W = Wkr;  C4 = 16;  wcol4 = col4 - 512; }
      const float4* wp = (const float4*)W + (size_t)k0 * C4 + wcol4;
      #pragma unroll
      for (int i = 0; i < 16; ++i) {
        float4 w4 = wp[(size_t)i * C4];
        #pragma unroll
        for (int b = 0; b < NB; ++b) fma4(acc[b], hidden[b*HID + k0 + i], w4);
      }
    }
    #pragma unroll
    for (int b = 0; b < NB; ++b) red_s[ksub][b][lane] = acc[b];
    __syncthreads();
    if (ksub == 0 && valid) {
      #pragma unroll
      for (int b = 0; b < NB; ++b) {
        float4 s = red_s[0][b][lane];
        #pragma unroll
        for (int j = 1; j < 4; ++j) {
          float4 v = red_s[j][b][lane];
          s.x += v.x; s.y += v.y; s.z += v.z; s.w += v.w;
        }
        *(float4*)(ws + WS_P1 + ((size_t)(gy*NB + b)*528 + col4)*4) = s;
      }
    }
  } else {
    const int bxc = bx - 576;
    if (bxc < 8192) {
      int b = bxc >> 11;
      int idx = (bxc & 2047) * 256 + threadIdx.x;
      float4 v = src_ckv[(size_t)b*(SS*CKV/4) + idx];
      dst_ckv[(size_t)b*(SK*CKV/4) + idx] = v;
      int off = idx * 4;
      int k = off >> 9, c = off & 511;
      *(ushort4*)(kvbf + ((size_t)b*SK + k)*KD + c) = f2bf4(v);
    } else {
      int bx2 = bxc - 8192;
      int b = bx2 >> 8;
      int idx = (bx2 & 255) * 256 + threadIdx.x;
      float4 v = src_kr[(size_t)b*(SS*RD/4) + idx];
      dst_kr[(size_t)b*(SK*RD/4) + idx] = v;
      int off = idx * 4;
      int k = off >> 6, rr = off & 63;
      *(ushort4*)(kvbf + ((size_t)b*SK + k)*KD + 512 + rr) = f2bf4(v);
    }
  }
}

// ------- L2: [bx<576] proj2 (self-reduced act from P1) | [else] reduce1 ------
__global__ __launch_bounds__(256)
void k_proj2r1(const float* __restrict__ Wuq,
               const float* __restrict__ Wqr,
               float* __restrict__ ws,
               float* __restrict__ out_ckv,
               float* __restrict__ out_kr) {
  __shared__ float4 red_s[4][NB][64];
  __shared__ float act_s[NB][64];
  unsigned short* kvbf = (unsigned short*)(ws + WS_KVBF);
  const int bx = blockIdx.x;
  const int tid = threadIdx.x;
  if (bx < 576) {
    const int gx = bx % 24, gy = bx / 24;
    {
      const int b = tid >> 6, i = tid & 63;
      const int k = gy * 64 + i;
      const float* base = ws + WS_P1 + (size_t)b*2112 + 512 + k;
      float s = 0.f;
      #pragma unroll 8
      for (int p = 0; p < NP1; ++p) s += base[(size_t)p*NB*2112];
      act_s[b][i] = s;
    }
    __syncthreads();
    const int lane = tid & 63, ksub = tid >> 6;
    const int col4 = gx * 64 + lane;
    const float* W; int C4, wcol4;
    if (col4 < 1024) { W = Wuq; C4 = 1024; wcol4 = col4; }
    else             { W = Wqr; C4 = 512;  wcol4 = col4 - 1024; }
    const float4* wp = (const float4*)W + (size_t)(gy*64 + ksub*16) * C4 + wcol4;
    float4 acc[NB] = {};
    #pragma unroll
    for (int i = 0; i < 16; ++i) {
      float4 w4 = wp[(size_t)i * C4];
      #pragma unroll
      for (int b = 0; b < NB; ++b) fma4(acc[b], act_s[b][ksub*16 + i], w4);
    }
    #pragma unroll
    for (int b = 0; b < NB; ++b) red_s[ksub][b][lane] = acc[b];
    __syncthreads();
    if (ksub == 0) {
      #pragma unroll
      for (int b = 0; b < NB; ++b) {
        float4 s = red_s[0][b][lane];
        #pragma unroll
        for (int j = 1; j < 4; ++j) {
          float4 v = red_s[j][b][lane];
          s.x += v.x; s.y += v.y; s.z += v.z; s.w += v.w;
        }
        *(float4*)(ws + WS_P2 + (size_t)(gy*NB + b)*6144 + col4*4) = s;
      }
    }
  } else {
    const int w = (bx - 576) * 256 + tid;
    if (w >= 528*NB) return;
    const int b = w / 528, col4 = w % 528;
    float4 s = {};
    #pragma unroll 8
    for (int p = 0; p < NP1; ++p) {
      float4 v = *(const float4*)(ws + WS_P1 + ((size_t)(p*NB + b)*528 + col4)*4);
      s.x += v.x; s.y += v.y; s.z += v.z; s.w += v.w;
    }
    if (col4 < 128) {
      *(float4*)(ws + WS_CKV + b*CKV + col4*4) = s;
      *(float4*)(out_ckv + (size_t)b*SK*CKV + (size_t)SS*CKV + col4*4) = s;
      *(ushort4*)(kvbf + ((size_t)b*SK + SS)*KD + col4*4) = f2bf4(s);
    } else if (col4 < 512) {
      *(float4*)(ws + WS_CQ + b*CQ + (col4 - 128)*4) = s;
    } else {
      const int c0 = (col4 - 512) * 4;
      const double LN1E4 = 9.210340371976184;
      int i0 = c0 >> 1;
      double a0 = 4096.0 * exp(-(double)i0 / 32.0 * LN1E4);
      double a1 = 4096.0 * exp(-(double)(i0 + 1) / 32.0 * LN1E4);
      float c0f = (float)cos(a0), s0f = (float)sin(a0);
      float c1f = (float)cos(a1), s1f = (float)sin(a1);
      float4 o;
      o.x = s.x*c0f - s.y*s0f;  o.y = s.x*s0f + s.y*c0f;
      o.z = s.z*c1f - s.w*s1f;  o.w = s.z*s1f + s.w*c1f;
      *(float4*)(ws + WS_KROPE + b*RD + c0) = o;
      *(float4*)(out_kr + (size_t)b*SK*RD + (size_t)SS*RD + c0) = o;
      *(ushort4*)(kvbf + ((size_t)b*SK + SS)*KD + 512 + c0) = f2bf4(o);
    }
  }
}

// -------- L3: q_abs = q_C @ W_UK^T (×SCALE) + bf16 q; q_R RoPE ---------------
__global__ __launch_bounds__(256)
void k_absorb_rope(const float* __restrict__ Wuk,
                   float* __restrict__ ws) {
  unsigned short* qbf = (unsigned short*)(ws + WS_QBF);
  const int bid = blockIdx.x, tid = threadIdx.x;
  if (bid < 256) {
    const int h = bid >> 3, cq = bid & 7;
    __shared__ float qc_s[NB][HD];
    __shared__ float part_s[NB][256];
    for (int e = tid; e < NB*HD; e += 256) {
      int b = e >> 7, d = e & 127;
      float v = 0.f;
      #pragma unroll
      for (int p = 0; p < NP2; ++p)
        v += ws[WS_P2 + (size_t)(p*NB + b)*6144 + h*HD + d];
      qc_s[b][d] = v;
    }
    __syncthreads();
    const int c = cq*64 + (tid & 63);
    const int dg = tid >> 6;
    const float4* wrow = (const float4*)(Wuk + (size_t)c*(NH*HD) + h*HD + dg*32);
    float acc[NB] = {0,0,0,0};
    #pragma unroll
    for (int d4 = 0; d4 < 8; ++d4) {
      float4 w4 = wrow[d4];
      #pragma unroll
      for (int b = 0; b < NB; ++b)
        acc[b] += dot4(w4, *(const float4*)&qc_s[b][dg*32 + d4*4]);
    }
    #pragma unroll
    for (int b = 0; b < NB; ++b) part_s[b][tid] = acc[b];
    __syncthreads();
    if (tid < 64) {
      #pragma unroll
      for (int b = 0; b < NB; ++b) {
        float v = (part_s[b][tid] + part_s[b][tid+64] + part_s[b][tid+128] + part_s[b][tid+192]) * SCALE_F;
        ws[WS_QABS + (size_t)(b*NH + h)*CKV + cq*64 + tid] = v;
        qbf[(size_t)(b*NH + h)*KD + cq*64 + tid] = f2bf(v);
      }
    }
  } else {
    const int b = bid - 256;
    const double LN1E4 = 9.210340371976184;
    for (int pid = tid; pid < NH*32; pid += 256) {
      int h = pid >> 5, i = pid & 31;
      float x1 = 0.f, x2 = 0.f;
      #pragma unroll
      for (int p = 0; p < NP2; ++p) {
        const float* base = ws + WS_P2 + (size_t)(p*NB + b)*6144 + 4096 + h*RD + 2*i;
        x1 += base[0]; x2 += base[1];
      }
      double ang = 4096.0 * exp(-(double)i / 32.0 * LN1E4);
      float cs = (float)cos(ang), sn = (float)sin(ang);
      float o0 = (x1*cs - x2*sn) * SCALE_F;
      float o1 = (x1*sn + x2*cs) * SCALE_F;
      ws[WS_QROPE + (b*NH + h)*RD + 2*i]     = o0;
      ws[WS_QROPE + (b*NH + h)*RD + 2*i + 1] = o1;
      qbf[(size_t)(b*NH + h)*KD + 512 + 2*i]     = f2bf(o0);
      qbf[(size_t)(b*NH + h)*KD + 512 + 2*i + 1] = f2bf(o1);
    }
  }
}

// ---------------- L4: fused flash attention (QK^T + softmax + PV) -----------
// grid (NPV=32 key-chunks, 4 c-quarters, 4 b) = 512 blocks, 256 thr.
// Chunk j covers keys [j*128, j*128+128); chunk 31 adds a 5th 32-key sub
// holding key 4096 (rest masked). Chunk-local softmax: m_j, l_j -> WS_ML;
// partial O -> OPART[j]. Exact LSE combine happens in k_uv2's pre-phase.
__global__ __launch_bounds__(256)
void k_attn(const float* __restrict__ mask, float* __restrict__ ws) {
  __shared__ unsigned short kv_s[32 * QKB_STR];   // 36.5 KB (aliased: P_s + kvT_s)
  __shared__ float S_s[32 * SFS];                 // 21.5 KB
  unsigned short* P_s  = kv_s;                    // [32][PSTR] bf16 (10.8 KB)
  unsigned short* kvT_s = kv_s + 32*PSTR;         // [128][TV_STR] bf16 (10 KB)
  const unsigned short* kvbf = (const unsigned short*)(ws + WS_KVBF);
  const unsigned short* qbf  = (const unsigned short*)(ws + WS_QBF);
  const int tid = threadIdx.x;
  const int j  = blockIdx.x;
  const int qy = blockIdx.y;
  const int b  = blockIdx.z;
  const int k0 = j * 128;
  const int NSUB = (j == NPV-1) ? 5 : 4;
  const int wid = tid >> 6, lane = tid & 63;
  const int l15 = lane & 15, lq = lane >> 4;

  // ---- phase 1: QK^T -> S_s (masked)
  const int m0 = (wid & 1) * 16;
  const int n0 = (wid >> 1) * 16;
  const unsigned short* arow = qbf + (size_t)(b*NH + m0 + l15)*KD + lq*8;
  for (int sc = 0; sc < NSUB; ++sc) {
    {  // stage 32 kv rows (guarded)
      const int r = tid >> 3, u0 = tid & 7;
      const int k = k0 + sc*32 + r;
      const unsigned short* ksrc = (k <= SS) ? (kvbf + ((size_t)b*SK + k)*KD) : nullptr;
      #pragma unroll
      for (int u8 = 0; u8 < 9; ++u8) {
        int u = (u0 + 8*u8) * 8;
        uint4 kvv = {0u, 0u, 0u, 0u};
        if (ksrc) kvv = *(const uint4*)(ksrc + u);
        *(uint4*)&kv_s[r*QKB_STR + u] = kvv;
      }
    }
    __syncthreads();
    const unsigned short* brow = &kv_s[(n0 + l15)*QKB_STR + lq*8];
    f32x4 acc = {0.f, 0.f, 0.f, 0.f};
    #pragma unroll
    for (int ks = 0; ks < 18; ++ks) {
      short8v a = *(const short8v*)(arow + ks*32);
      short8v bb = *(const short8v*)(brow + ks*32);
      acc = __builtin_amdgcn_mfma_f32_16x16x32_bf16(a, bb, acc, 0, 0, 0);
    }
    const int kk = sc*32 + n0 + l15;           // key index within chunk
    const bool vkey = (k0 + kk) <= SS;
    #pragma unroll
    for (int r = 0; r < 4; ++r)
      S_s[(m0 + lq*4 + r)*SFS + kk] = vkey ? acc[r] : -1e30f;
    __syncthreads();
  }

  // ---- phase 2: chunk-local softmax -> P_s bf16; (m_j,l_j) -> ML (qy==0)
  {
    const int row = tid >> 3, i8 = tid & 7;    // 32 rows × 8 lanes
    const int NK = NSUB * 32;
    float m = -INFINITY;
    for (int kk = i8; kk < NK; kk += 8) {
      int kgl = k0 + kk;
      float mv = (kgl < SK) ? mask[(size_t)b*SK + kgl] : 0.f;
      float v = S_s[row*SFS + kk] + mv * (-1e9f);
      S_s[row*SFS + kk] = v;                   // store masked score back
      m = fmaxf(m, v);
    }
    m = fmaxf(m, __shfl_xor(m, 1));
    m = fmaxf(m, __shfl_xor(m, 2));
    m = fmaxf(m, __shfl_xor(m, 4));
    float l = 0.f;
    for (int kk = i8; kk < NK; kk += 8) {
      float e = __expf(S_s[row*SFS + kk] - m);
      l += e;
      P_s[row*PSTR + kk] = f2bf(e);
    }
    l += __shfl_xor(l, 1);
    l += __shfl_xor(l, 2);
    l += __shfl_xor(l, 4);
    if (i8 == 0 && qy == 0) {
      float* ml = ws + WS_ML + ((size_t)(b*NH + row)*NPV + j)*2;
      ml[0] = m; ml[1] = l;
    }
  }
  __syncthreads();

  // ---- phase 3: PV for this c-quarter (kvT transpose per 32-key sub)
  const int c0 = qy * 128;
  f32x4 acc4[4] = {{0,0,0,0},{0,0,0,0},{0,0,0,0},{0,0,0,0}};
  const int kk_st = tid & 31, cgrp = tid >> 5;
  for (int sc = 0; sc < NSUB; ++sc) {
    {  // stage kvT [128 c][32 k] (guarded)
      const int k = k0 + sc*32 + kk_st;
      ushort4 v0 = {0,0,0,0}, v1 = {0,0,0,0}, v2 = {0,0,0,0}, v3 = {0,0,0,0};
      if (k <= SS) {
        const unsigned short* src = kvbf + ((size_t)b*SK + k)*KD + c0 + cgrp*16;
        v0 = *(const ushort4*)(src);
        v1 = *(const ushort4*)(src + 4);
        v2 = *(const ushort4*)(src + 8);
        v3 = *(const ushort4*)(src + 12);
      }
      int cb = cgrp*16;
      kvT_s[(cb+ 0)*TV_STR + kk_st] = v0.x;
      kvT_s[(cb+ 1)*TV_STR + kk_st] = v0.y;
      kvT_s[(cb+ 2)*TV_STR + kk_st] = v0.z;
      kvT_s[(cb+ 3)*TV_STR + kk_st] = v0.w;
      kvT_s[(cb+ 4)*TV_STR + kk_st] = v1.x;
      kvT_s[(cb+ 5)*TV_STR + kk_st] = v1.y;
      kvT_s[(cb+ 6)*TV_STR + kk_st] = v1.z;
      kvT_s[(cb+ 7)*TV_STR + kk_st] = v1.w;
      kvT_s[(cb+ 8)*TV_STR + kk_st] = v2.x;
      kvT_s[(cb+ 9)*TV_STR + kk_st] = v2.y;
      kvT_s[(cb+10)*TV_STR + kk_st] = v2.z;
      kvT_s[(cb+11)*TV_STR + kk_st] = v2.w;
      kvT_s[(cb+12)*TV_STR + kk_st] = v3.x;
      kvT_s[(cb+13)*TV_STR + kk_st] = v3.y;
      kvT_s[(cb+14)*TV_STR + kk_st] = v3.z;
      kvT_s[(cb+15)*TV_STR + kk_st] = v3.w;
    }
    __syncthreads();
    short8v a = *(const short8v*)(&P_s[(m0 + l15)*PSTR + sc*32 + lq*8]);
    #pragma unroll
    for (int t = 0; t < 4; ++t) {
      const int nt = (wid >> 1) + 2*t;         // n-tiles {0,2,4,6} or {1,3,5,7}
      const unsigned short* brow = &kvT_s[(nt*16 + l15)*TV_STR + lq*8];
      short8v bb = *(const short8v*)(brow);
      acc4[t] = __builtin_amdgcn_mfma_f32_16x16x32_bf16(a, bb, acc4[t], 0, 0, 0);
    }
    __syncthreads();
  }
  #pragma unroll
  for (int t = 0; t < 4; ++t) {
    const int nt = (wid >> 1) + 2*t;
    const int c = c0 + nt*16 + l15;
    #pragma unroll
    for (int r = 0; r < 4; ++r) {
      int h = m0 + lq*4 + r;
      ws[WS_OPART + (((size_t)j*NB + b)*NH + h)*CKV + c] = acc4[t][r];
    }
  }
}

// ------- L5: uv with LSE-combine pre-phase (reduce + rescale) ----------------
__global__ __launch_bounds__(256)
void k_uv2(const float* __restrict__ Wuv, float* __restrict__ ws) {
  __shared__ float4 red_s[4][NB][64];
  __shared__ float ol_s[NB][2][32];
  const int tid = threadIdx.x;
  const int x = blockIdx.x & 15, y = blockIdx.x >> 4;
  {
    const int b = tid >> 6, hh = (tid >> 5) & 1, ci = tid & 31;
    const int h = 2*x + hh, c = y*32 + ci;
    const float* ml = ws + WS_ML + (size_t)(b*NH + h)*NPV*2;
    float M = -INFINITY;
    #pragma unroll 8
    for (int p = 0; p < NPV; ++p) M = fmaxf(M, ml[p*2]);
    const float* base = ws + WS_OPART + ((size_t)b*NH + h)*CKV + c;
    float s = 0.f, L = 0.f;
    #pragma unroll 4
    for (int p = 0; p < NPV; ++p) {
      float w = __expf(ml[p*2] - M);
      L += w * ml[p*2 + 1];
      s += w * base[(size_t)p*(NB*NH*CKV)];
    }
    ol_s[b][hh][ci] = s / L;
  }
  __syncthreads();
  const int lane = tid & 63, csub = tid >> 6;
  const int col4 = x * 64 + lane;
  const int hh = (col4 >> 5) & 1;
  const float4* wp = (const float4*)Wuv + (size_t)(y*32 + csub*8) * 1024 + col4;
  float4 acc[NB] = {};
  #pragma unroll
  for (int i = 0; i < 8; ++i) {
    float4 w4 = wp[(size_t)i * 1024];
    #pragma unroll
    for (int b = 0; b < NB; ++b)
      fma4(acc[b], ol_s[b][hh][csub*8 + i], w4);
  }
  #pragma unroll
  for (int b = 0; b < NB; ++b) red_s[csub][b][lane] = acc[b];
  __syncthreads();
  if (csub == 0) {
    #pragma unroll
    for (int b = 0; b < NB; ++b) {
      float4 s = red_s[0][b][lane];
      #pragma unroll
      for (int j = 1; j < 4; ++j) {
        float4 v = red_s[j][b][lane];
        s.x += v.x; s.y += v.y; s.z += v.z; s.w += v.w;
      }
      *(float4*)(ws + WS_UVPART + (size_t)(y*NB + b)*HID + col4*4) = s;
    }
  }
}

// ------- L6: wo with UVPART self-reduce pre-phase ----------------------------
__global__ __launch_bounds__(256)
void k_wo2(const float* __restrict__ Wo, float* __restrict__ ws) {
  __shared__ float4 red_s[4][NB][64];
  __shared__ float at_s[NB][128];
  const int tid = threadIdx.x;
  const int x = blockIdx.x & 15, y = blockIdx.x >> 4;
  {
    const int b = tid >> 6, q = tid & 63;
    #pragma unroll
    for (int e = 0; e < 2; ++e) {
      int idx = q*2 + e;
      const float* base = ws + WS_UVPART + (size_t)b*HID + y*128 + idx;
      float s = 0.f;
      #pragma unroll
      for (int p = 0; p < NUV; ++p) s += base[(size_t)p*(NB*HID)];
      at_s[b][idx] = s;
    }
  }
  __syncthreads();
  const int lane = tid & 63, ksub = tid >> 6;
  const int col4 = x * 64 + lane;
  const float4* wp = (const float4*)Wo + (size_t)(y*128 + ksub*32) * 1024 + col4;
  float4 acc[NB] = {};
  #pragma unroll 8
  for (int i = 0; i < 32; ++i) {
    float4 w4 = wp[(size_t)i * 1024];
    #pragma unroll
    for (int b = 0; b < NB; ++b)
      fma4(acc[b], at_s[b][ksub*32 + i], w4);
  }
  #pragma unroll
  for (int b = 0; b < NB; ++b) red_s[ksub][b][lane] = acc[b];
  __syncthreads();
  if (ksub == 0) {
    #pragma unroll
    for (int b = 0; b < NB; ++b) {
      float4 s = red_s[0][b][lane];
      #pragma unroll
      for (int j = 1; j < 4; ++j) {
        float4 v = red_s[j][b][lane];
        s.x += v.x; s.y += v.y; s.z += v.z; s.w += v.w;
      }
      *(float4*)(ws + WS_WOPART + (size_t)(y*NB + b)*HID + col4*4) = s;
    }
  }
}

// ---------------- L7: out = sum_p WOPART[p] ----------------------------------
__global__ __launch_bounds__(256)
void k_reduce5(const float* __restrict__ ws, float* __restrict__ out) {
  const int idx = blockIdx.x * 256 + threadIdx.x;
  float4 s = {};
  #pragma unroll 8
  for (int p = 0; p < NWO; ++p) {
    float4 v = *(const float4*)(ws + WS_WOPART + (size_t)p*(NB*HID) + (size_t)idx*4);
    s.x += v.x; s.y += v.y; s.z += v.z; s.w += v.w;
  }
  *(float4*)(out + (size_t)idx*4) = s;
}

extern "C" void kernel_launch(void* const* d_in, const int* in_sizes, int n_in,
                              void* d_out, int out_size, void* d_ws, size_t ws_size,
                              hipStream_t stream) {
  (void)in_sizes; (void)n_in; (void)out_size; (void)ws_size;
  const float* hidden = (const float*)d_in[0];
  const float* mask   = (const float*)d_in[1];
  const float* ckv_c  = (const float*)d_in[2];
  const float* kr_c   = (const float*)d_in[3];
  const float* Wdkv   = (const float*)d_in[4];
  const float* Wuk    = (const float*)d_in[5];
  const float* Wuv    = (const float*)d_in[6];
  const float* Wdq    = (const float*)d_in[7];
  const float* Wuq    = (const float*)d_in[8];
  const float* Wqr    = (const float*)d_in[9];
  const float* Wkr    = (const float*)d_in[10];
  const float* Wo     = (const float*)d_in[11];
  float* out = (float*)d_out;
  float* ws  = (float*)d_ws;
  float* out_ckv = out + NB*HID;
  float* out_kr  = out + NB*HID + (size_t)NB*SK*CKV;

  k_proj1copy<<<9792, 256, 0, stream>>>(hidden, Wdkv, Wdq, Wkr, ws,
                                        (const float4*)ckv_c, (const float4*)kr_c,
                                        (float4*)out_ckv, (float4*)out_kr);
  k_proj2r1<<<585, 256, 0, stream>>>(Wuq, Wqr, ws, out_ckv, out_kr);
  k_absorb_rope<<<260, 256, 0, stream>>>(Wuk, ws);
  k_attn<<<dim3(NPV, 4, 4), 256, 0, stream>>>(mask, ws);
  k_uv2<<<256, 256, 0, stream>>>(Wuv, ws);
  k_wo2<<<512, 256, 0, stream>>>(Wo, ws);
  k_reduce5<<<16, 256, 0, stream>>>(ws, out);
}

// Round 18
// 107.125 us; speedup vs baseline: 1.1247x; 1.1247x over previous
//
#include <hip/hip_runtime.h>
#include <math.h>

#define NB 4
#define HID 4096
#define CKV 512
#define CQ 1536
#define NH 32
#define HD 128
#define RD 64
#define SS 4096
#define SK 4097
#define SKP 4100

#define SCALE_F 0.07216878364870322f  // 1/sqrt(192)

#define NP1 64   // proj1 k-partials
#define NP2 24   // proj2 k-partials
#define NPV 32   // pv key-chunks (128 keys; chunk 31 adds key 4096)
#define NUV 16   // uv c-partials
#define NWO 32   // wo k-partials

#define KD   576      // latent 512 + rope 64, contiguous bf16 rows
#define QKB_STR 584   // kv LDS bf16 row stride
#define TV_STR 40     // kvT LDS row stride in u16
#define SFS  168      // S_s row stride (f32)
#define PSTR 168      // P_s row stride (bf16)

typedef __attribute__((ext_vector_type(8))) short short8v;
typedef __attribute__((ext_vector_type(4))) float f32x4;

// workspace offsets (floats). ALL regions disjoint (ws is 256 MB).
enum : int {
  WS_QABS  = 0,
  WS_QROPE = WS_QABS + NB*NH*CKV,
  WS_KROPE = WS_QROPE + NB*NH*RD,
  WS_CKV   = WS_KROPE + NB*RD,
  WS_CQ    = WS_CKV + NB*CKV,
  WS_SCA   = WS_CQ + NB*CQ,            // [NB][NH][SKP] raw scores (f32)
  WS_P1    = WS_SCA + NB*NH*SKP,
  WS_P2    = WS_P1 + NP1*NB*528*4,
  WS_OPART = WS_P2 + NP2*NB*6144,      // [NPV][NB][NH][CKV]
  WS_UVPART= WS_OPART + NPV*NB*NH*CKV,
  WS_WOPART= WS_UVPART + NUV*NB*HID,
  WS_KVBF  = WS_WOPART + NWO*NB*HID,   // bf16 [NB][SK][576]
  WS_QBF   = WS_KVBF + (NB*SK*KD)/2,   // bf16 [NB][NH][576]
  WS_ML    = WS_QBF + (NB*NH*KD)/2,    // [NB][NH][NPV][2] (m_j, l_j)
  WS_TOTAL = WS_ML + NB*NH*NPV*2
};

__device__ inline void fma4(float4& a, float s, const float4& v) {
  a.x += s*v.x; a.y += s*v.y; a.z += s*v.z; a.w += s*v.w;
}
__device__ inline float dot4(const float4& a, const float4& b) {
  return a.x*b.x + a.y*b.y + a.z*b.z + a.w*b.w;
}
__device__ inline unsigned short f2bf(float f) {
  union { float f; unsigned int u; } v; v.f = f;
  unsigned int r = v.u + 0x7FFFu + ((v.u >> 16) & 1u);
  return (unsigned short)(r >> 16);
}
__device__ inline ushort4 f2bf4(float4 v) {
  ushort4 r; r.x = f2bf(v.x); r.y = f2bf(v.y); r.z = f2bf(v.z); r.w = f2bf(v.w);
  return r;
}
__device__ inline float bf2f(unsigned short u) {
  union { unsigned int u; float f; } v; v.u = ((unsigned int)u) << 16;
  return v.f;
}

// ------- L1: [bx<576] proj1 -> P1 partials | [else] cache copy + bf16 copy --
__global__ __launch_bounds__(256)
void k_proj1copy(const float* __restrict__ hidden,
                 const float* __restrict__ Wdkv,
                 const float* __restrict__ Wdq,
                 const float* __restrict__ Wkr,
                 float* __restrict__ ws,
                 const float4* __restrict__ src_ckv,
                 const float4* __restrict__ src_kr,
                 float4* __restrict__ dst_ckv,
                 float4* __restrict__ dst_kr) {
  __shared__ float4 red_s[4][NB][64];
  unsigned short* kvbf = (unsigned short*)(ws + WS_KVBF);
  const int bx = blockIdx.x;
  if (bx < 576) {
    const int gx = bx % 9, gy = bx / 9;
    const int lane = threadIdx.x & 63, ksub = threadIdx.x >> 6;
    const int col4 = gx * 64 + lane;
    const int k0 = gy * 64 + ksub * 16;
    const bool valid = col4 < 528;
    float4 acc[NB] = {};
    if (valid) {
      const float* W; int C4, wcol4;
      if (col4 < 128)      { W = Wdkv; C4 = 128; wcol4 = col4; }
      else if (col4 < 512) { W = Wdq;  C4 = 384; wcol4 = col4 - 128; }
      else                 { W = Wkr;  C4 = 16;  wcol4 = col4 - 512; }
      const float4* wp = (const float4*)W + (size_t)k0 * C4 + wcol4;
      #pragma unroll
      for (int i = 0; i < 16; ++i) {
        float4 w4 = wp[(size_t)i * C4];
        #pragma unroll
        for (int b = 0; b < NB; ++b) fma4(acc[b], hidden[b*HID + k0 + i], w4);
      }
    }
    #pragma unroll
    for (int b = 0; b < NB; ++b) red_s[ksub][b][lane] = acc[b];
    __syncthreads();
    if (ksub == 0 && valid) {
      #pragma unroll
      for (int b = 0; b < NB; ++b) {
        float4 s = red_s[0][b][lane];
        #pragma unroll
        for (int j = 1; j < 4; ++j) {
          float4 v = red_s[j][b][lane];
          s.x += v.x; s.y += v.y; s.z += v.z; s.w += v.w;
        }
        *(float4*)(ws + WS_P1 + ((size_t)(gy*NB + b)*528 + col4)*4) = s;
      }
    }
  } else {
    const int bxc = bx - 576;
    if (bxc < 8192) {
      int b = bxc >> 11;
      int idx = (bxc & 2047) * 256 + threadIdx.x;
      float4 v = src_ckv[(size_t)b*(SS*CKV/4) + idx];
      dst_ckv[(size_t)b*(SK*CKV/4) + idx] = v;
      int off = idx * 4;
      int k = off >> 9, c = off & 511;
      *(ushort4*)(kvbf + ((size_t)b*SK + k)*KD + c) = f2bf4(v);
    } else {
      int bx2 = bxc - 8192;
      int b = bx2 >> 8;
      int idx = (bx2 & 255) * 256 + threadIdx.x;
      float4 v = src_kr[(size_t)b*(SS*RD/4) + idx];
      dst_kr[(size_t)b*(SK*RD/4) + idx] = v;
      int off = idx * 4;
      int k = off >> 6, rr = off & 63;
      *(ushort4*)(kvbf + ((size_t)b*SK + k)*KD + 512 + rr) = f2bf4(v);
    }
  }
}

// ------- L2: [bx<576] proj2 (self-reduced act from P1) | [else] reduce1 ------
__global__ __launch_bounds__(256)
void k_proj2r1(const float* __restrict__ Wuq,
               const float* __restrict__ Wqr,
               float* __restrict__ ws,
               float* __restrict__ out_ckv,
               float* __restrict__ out_kr) {
  __shared__ float4 red_s[4][NB][64];
  __shared__ float act_s[NB][64];
  unsigned short* kvbf = (unsigned short*)(ws + WS_KVBF);
  const int bx = blockIdx.x;
  const int tid = threadIdx.x;
  if (bx < 576) {
    const int gx = bx % 24, gy = bx / 24;
    {
      const int b = tid >> 6, i = tid & 63;
      const int k = gy * 64 + i;
      const float* base = ws + WS_P1 + (size_t)b*2112 + 512 + k;
      float s = 0.f;
      #pragma unroll 8
      for (int p = 0; p < NP1; ++p) s += base[(size_t)p*NB*2112];
      act_s[b][i] = s;
    }
    __syncthreads();
    const int lane = tid & 63, ksub = tid >> 6;
    const int col4 = gx * 64 + lane;
    const float* W; int C4, wcol4;
    if (col4 < 1024) { W = Wuq; C4 = 1024; wcol4 = col4; }
    else             { W = Wqr; C4 = 512;  wcol4 = col4 - 1024; }
    const float4* wp = (const float4*)W + (size_t)(gy*64 + ksub*16) * C4 + wcol4;
    float4 acc[NB] = {};
    #pragma unroll
    for (int i = 0; i < 16; ++i) {
      float4 w4 = wp[(size_t)i * C4];
      #pragma unroll
      for (int b = 0; b < NB; ++b) fma4(acc[b], act_s[b][ksub*16 + i], w4);
    }
    #pragma unroll
    for (int b = 0; b < NB; ++b) red_s[ksub][b][lane] = acc[b];
    __syncthreads();
    if (ksub == 0) {
      #pragma unroll
      for (int b = 0; b < NB; ++b) {
        float4 s = red_s[0][b][lane];
        #pragma unroll
        for (int j = 1; j < 4; ++j) {
          float4 v = red_s[j][b][lane];
          s.x += v.x; s.y += v.y; s.z += v.z; s.w += v.w;
        }
        *(float4*)(ws + WS_P2 + (size_t)(gy*NB + b)*6144 + col4*4) = s;
      }
    }
  } else {
    const int w = (bx - 576) * 256 + tid;
    if (w >= 528*NB) return;
    const int b = w / 528, col4 = w % 528;
    float4 s = {};
    #pragma unroll 8
    for (int p = 0; p < NP1; ++p) {
      float4 v = *(const float4*)(ws + WS_P1 + ((size_t)(p*NB + b)*528 + col4)*4);
      s.x += v.x; s.y += v.y; s.z += v.z; s.w += v.w;
    }
    if (col4 < 128) {
      *(float4*)(ws + WS_CKV + b*CKV + col4*4) = s;
      *(float4*)(out_ckv + (size_t)b*SK*CKV + (size_t)SS*CKV + col4*4) = s;
      *(ushort4*)(kvbf + ((size_t)b*SK + SS)*KD + col4*4) = f2bf4(s);
    } else if (col4 < 512) {
      *(float4*)(ws + WS_CQ + b*CQ + (col4 - 128)*4) = s;
    } else {
      const int c0 = (col4 - 512) * 4;
      const double LN1E4 = 9.210340371976184;
      int i0 = c0 >> 1;
      double a0 = 4096.0 * exp(-(double)i0 / 32.0 * LN1E4);
      double a1 = 4096.0 * exp(-(double)(i0 + 1) / 32.0 * LN1E4);
      float c0f = (float)cos(a0), s0f = (float)sin(a0);
      float c1f = (float)cos(a1), s1f = (float)sin(a1);
      float4 o;
      o.x = s.x*c0f - s.y*s0f;  o.y = s.x*s0f + s.y*c0f;
      o.z = s.z*c1f - s.w*s1f;  o.w = s.z*s1f + s.w*c1f;
      *(float4*)(ws + WS_KROPE + b*RD + c0) = o;
      *(float4*)(out_kr + (size_t)b*SK*RD + (size_t)SS*RD + c0) = o;
      *(ushort4*)(kvbf + ((size_t)b*SK + SS)*KD + 512 + c0) = f2bf4(o);
    }
  }
}

// -------- L3: q_abs = q_C @ W_UK^T (×SCALE) + bf16 q; q_R RoPE ---------------
__global__ __launch_bounds__(256)
void k_absorb_rope(const float* __restrict__ Wuk,
                   float* __restrict__ ws) {
  unsigned short* qbf = (unsigned short*)(ws + WS_QBF);
  const int bid = blockIdx.x, tid = threadIdx.x;
  if (bid < 256) {
    const int h = bid >> 3, cq = bid & 7;
    __shared__ float qc_s[NB][HD];
    __shared__ float part_s[NB][256];
    for (int e = tid; e < NB*HD; e += 256) {
      int b = e >> 7, d = e & 127;
      float v = 0.f;
      #pragma unroll
      for (int p = 0; p < NP2; ++p)
        v += ws[WS_P2 + (size_t)(p*NB + b)*6144 + h*HD + d];
      qc_s[b][d] = v;
    }
    __syncthreads();
    const int c = cq*64 + (tid & 63);
    const int dg = tid >> 6;
    const float4* wrow = (const float4*)(Wuk + (size_t)c*(NH*HD) + h*HD + dg*32);
    float acc[NB] = {0,0,0,0};
    #pragma unroll
    for (int d4 = 0; d4 < 8; ++d4) {
      float4 w4 = wrow[d4];
      #pragma unroll
      for (int b = 0; b < NB; ++b)
        acc[b] += dot4(w4, *(const float4*)&qc_s[b][dg*32 + d4*4]);
    }
    #pragma unroll
    for (int b = 0; b < NB; ++b) part_s[b][tid] = acc[b];
    __syncthreads();
    if (tid < 64) {
      #pragma unroll
      for (int b = 0; b < NB; ++b) {
        float v = (part_s[b][tid] + part_s[b][tid+64] + part_s[b][tid+128] + part_s[b][tid+192]) * SCALE_F;
        ws[WS_QABS + (size_t)(b*NH + h)*CKV + cq*64 + tid] = v;
        qbf[(size_t)(b*NH + h)*KD + cq*64 + tid] = f2bf(v);
      }
    }
  } else {
    const int b = bid - 256;
    const double LN1E4 = 9.210340371976184;
    for (int pid = tid; pid < NH*32; pid += 256) {
      int h = pid >> 5, i = pid & 31;
      float x1 = 0.f, x2 = 0.f;
      #pragma unroll
      for (int p = 0; p < NP2; ++p) {
        const float* base = ws + WS_P2 + (size_t)(p*NB + b)*6144 + 4096 + h*RD + 2*i;
        x1 += base[0]; x2 += base[1];
      }
      double ang = 4096.0 * exp(-(double)i / 32.0 * LN1E4);
      float cs = (float)cos(ang), sn = (float)sin(ang);
      float o0 = (x1*cs - x2*sn) * SCALE_F;
      float o1 = (x1*sn + x2*cs) * SCALE_F;
      ws[WS_QROPE + (b*NH + h)*RD + 2*i]     = o0;
      ws[WS_QROPE + (b*NH + h)*RD + 2*i + 1] = o1;
      qbf[(size_t)(b*NH + h)*KD + 512 + 2*i]     = f2bf(o0);
      qbf[(size_t)(b*NH + h)*KD + 512 + 2*i + 1] = f2bf(o1);
    }
  }
}

// ---------------- L4: scores via MFMA bf16 — q from global (R16 proven) ------
__global__ __launch_bounds__(256)
void k_scores_mfma(float* __restrict__ ws) {
  __shared__ unsigned short kv_s[32 * QKB_STR];
  const unsigned short* kvbf = (const unsigned short*)(ws + WS_KVBF);
  const unsigned short* qbf  = (const unsigned short*)(ws + WS_QBF);
  const int tid = threadIdx.x;
  const int b  = blockIdx.y;
  const int k0 = blockIdx.x * 32;
  {
    const int r = tid >> 3, u0 = tid & 7;
    const int k = k0 + r;
    const unsigned short* ksrc = (k <= SS) ? (kvbf + ((size_t)b*SK + k)*KD) : nullptr;
    #pragma unroll
    for (int j = 0; j < 9; ++j) {
      int u = (u0 + 8*j) * 8;
      uint4 kvv = {0u, 0u, 0u, 0u};
      if (ksrc) kvv = *(const uint4*)(ksrc + u);
      *(uint4*)&kv_s[r*QKB_STR + u] = kvv;
    }
  }
  __syncthreads();
  const int wid = tid >> 6, lane = tid & 63;
  const int m0 = (wid & 1) * 16;
  const int n0 = (wid >> 1) * 16;
  const int l15 = lane & 15, lq = lane >> 4;
  const unsigned short* arow = qbf + (size_t)(b*NH + m0 + l15)*KD + lq*8;
  const unsigned short* brow = &kv_s[(n0 + l15)*QKB_STR + lq*8];
  f32x4 acc = {0.f, 0.f, 0.f, 0.f};
  #pragma unroll
  for (int ks = 0; ks < 18; ++ks) {
    short8v a = *(const short8v*)(arow + ks*32);
    short8v bb = *(const short8v*)(brow + ks*32);
    acc = __builtin_amdgcn_mfma_f32_16x16x32_bf16(a, bb, acc, 0, 0, 0);
  }
  const int key = k0 + n0 + l15;
  if (key <= SS) {
    #pragma unroll
    for (int r = 0; r < 4; ++r) {
      int h = m0 + lq*4 + r;
      ws[WS_SCA + (size_t)(b*NH + h)*SKP + key] = acc[r];
    }
  }
}

// ---------------- L5: pvflash — chunk-local softmax + PV MFMA ----------------
// grid (NPV=32, 4 c-quarters, 4 b) = 512 blocks. Chunk j: keys [128j,128j+128)
// (+key 4096 for j=31). Local softmax (m_j,l_j -> ML from qy==0), bf16 P in
// LDS, then kvT-transpose + MFMA PV (R16 proven). Combine in k_uv2 (R17 proven).
__global__ __launch_bounds__(256)
void k_pvflash(const float* __restrict__ mask, float* __restrict__ ws) {
  __shared__ float S_s[32 * SFS];                 // 21.5 KB
  __shared__ unsigned short P_s[32 * PSTR];       // 10.8 KB
  __shared__ unsigned short kvT_s[128 * TV_STR];  // 10 KB
  const unsigned short* kvbf = (const unsigned short*)(ws + WS_KVBF);
  const int tid = threadIdx.x;
  const int j  = blockIdx.x;
  const int qy = blockIdx.y;
  const int b  = blockIdx.z;
  const int k0 = j * 128;
  const int NSUB = (j == NPV-1) ? 5 : 4;
  const int NK = NSUB * 32;
  const int wid = tid >> 6, lane = tid & 63;
  const int l15 = lane & 15, lq = lane >> 4;
  const int m0 = (wid & 1) * 16;

  // ---- phase 1: load S chunk (+mask, guards), local softmax -> P_s, ML
  {
    const int row = tid >> 3, i8 = tid & 7;
    const float* srow = ws + WS_SCA + (size_t)(b*NH + row)*SKP;
    const float* mrow = mask + (size_t)b*SK;
    float m = -INFINITY;
    for (int kk = i8; kk < NK; kk += 8) {
      int kgl = k0 + kk;
      float v = (kgl < SK) ? (srow[kgl] + mrow[kgl] * (-1e9f)) : -1e30f;
      S_s[row*SFS + kk] = v;
      m = fmaxf(m, v);
    }
    m = fmaxf(m, __shfl_xor(m, 1));
    m = fmaxf(m, __shfl_xor(m, 2));
    m = fmaxf(m, __shfl_xor(m, 4));
    float l = 0.f;
    for (int kk = i8; kk < NK; kk += 8) {
      float e = __expf(S_s[row*SFS + kk] - m);
      l += e;
      P_s[row*PSTR + kk] = f2bf(e);
    }
    l += __shfl_xor(l, 1);
    l += __shfl_xor(l, 2);
    l += __shfl_xor(l, 4);
    if (i8 == 0 && qy == 0) {
      float* ml = ws + WS_ML + ((size_t)(b*NH + row)*NPV + j)*2;
      ml[0] = m; ml[1] = l;
    }
  }
  __syncthreads();

  // ---- phase 2: PV for this c-quarter (kvT transpose per 32-key sub)
  const int c0 = qy * 128;
  f32x4 acc4[4] = {{0,0,0,0},{0,0,0,0},{0,0,0,0},{0,0,0,0}};
  const int kk_st = tid & 31, cgrp = tid >> 5;
  for (int sc = 0; sc < NSUB; ++sc) {
    {
      const int k = k0 + sc*32 + kk_st;
      ushort4 v0 = {0,0,0,0}, v1 = {0,0,0,0}, v2 = {0,0,0,0}, v3 = {0,0,0,0};
      if (k <= SS) {
        const unsigned short* src = kvbf + ((size_t)b*SK + k)*KD + c0 + cgrp*16;
        v0 = *(const ushort4*)(src);
        v1 = *(const ushort4*)(src + 4);
        v2 = *(const ushort4*)(src + 8);
        v3 = *(const ushort4*)(src + 12);
      }
      int cb = cgrp*16;
      kvT_s[(cb+ 0)*TV_STR + kk_st] = v0.x;
      kvT_s[(cb+ 1)*TV_STR + kk_st] = v0.y;
      kvT_s[(cb+ 2)*TV_STR + kk_st] = v0.z;
      kvT_s[(cb+ 3)*TV_STR + kk_st] = v0.w;
      kvT_s[(cb+ 4)*TV_STR + kk_st] = v1.x;
      kvT_s[(cb+ 5)*TV_STR + kk_st] = v1.y;
      kvT_s[(cb+ 6)*TV_STR + kk_st] = v1.z;
      kvT_s[(cb+ 7)*TV_STR + kk_st] = v1.w;
      kvT_s[(cb+ 8)*TV_STR + kk_st] = v2.x;
      kvT_s[(cb+ 9)*TV_STR + kk_st] = v2.y;
      kvT_s[(cb+10)*TV_STR + kk_st] = v2.z;
      kvT_s[(cb+11)*TV_STR + kk_st] = v2.w;
      kvT_s[(cb+12)*TV_STR + kk_st] = v3.x;
      kvT_s[(cb+13)*TV_STR + kk_st] = v3.y;
      kvT_s[(cb+14)*TV_STR + kk_st] = v3.z;
      kvT_s[(cb+15)*TV_STR + kk_st] = v3.w;
    }
    __syncthreads();
    short8v a = *(const short8v*)(&P_s[(m0 + l15)*PSTR + sc*32 + lq*8]);
    #pragma unroll
    for (int t = 0; t < 4; ++t) {
      const int nt = (wid >> 1) + 2*t;
      const unsigned short* brow = &kvT_s[(nt*16 + l15)*TV_STR + lq*8];
      short8v bb = *(const short8v*)(brow);
      acc4[t] = __builtin_amdgcn_mfma_f32_16x16x32_bf16(a, bb, acc4[t], 0, 0, 0);
    }
    __syncthreads();
  }
  #pragma unroll
  for (int t = 0; t < 4; ++t) {
    const int nt = (wid >> 1) + 2*t;
    const int c = c0 + nt*16 + l15;
    #pragma unroll
    for (int r = 0; r < 4; ++r) {
      int h = m0 + lq*4 + r;
      ws[WS_OPART + (((size_t)j*NB + b)*NH + h)*CKV + c] = acc4[t][r];
    }
  }
}

// ------- L6: uv with LSE-combine pre-phase (R17 proven) ----------------------
__global__ __launch_bounds__(256)
void k_uv2(const float* __restrict__ Wuv, float* __restrict__ ws) {
  __shared__ float4 red_s[4][NB][64];
  __shared__ float ol_s[NB][2][32];
  const int tid = threadIdx.x;
  const int x = blockIdx.x & 15, y = blockIdx.x >> 4;
  {
    const int b = tid >> 6, hh = (tid >> 5) & 1, ci = tid & 31;
    const int h = 2*x + hh, c = y*32 + ci;
    const float* ml = ws + WS_ML + (size_t)(b*NH + h)*NPV*2;
    float M = -INFINITY;
    #pragma unroll 8
    for (int p = 0; p < NPV; ++p) M = fmaxf(M, ml[p*2]);
    const float* base = ws + WS_OPART + ((size_t)b*NH + h)*CKV + c;
    float s = 0.f, L = 0.f;
    #pragma unroll 4
    for (int p = 0; p < NPV; ++p) {
      float w = __expf(ml[p*2] - M);
      L += w * ml[p*2 + 1];
      s += w * base[(size_t)p*(NB*NH*CKV)];
    }
    ol_s[b][hh][ci] = s / L;
  }
  __syncthreads();
  const int lane = tid & 63, csub = tid >> 6;
  const int col4 = x * 64 + lane;
  const int hh = (col4 >> 5) & 1;
  const float4* wp = (const float4*)Wuv + (size_t)(y*32 + csub*8) * 1024 + col4;
  float4 acc[NB] = {};
  #pragma unroll
  for (int i = 0; i < 8; ++i) {
    float4 w4 = wp[(size_t)i * 1024];
    #pragma unroll
    for (int b = 0; b < NB; ++b)
      fma4(acc[b], ol_s[b][hh][csub*8 + i], w4);
  }
  #pragma unroll
  for (int b = 0; b < NB; ++b) red_s[csub][b][lane] = acc[b];
  __syncthreads();
  if (csub == 0) {
    #pragma unroll
    for (int b = 0; b < NB; ++b) {
      float4 s = red_s[0][b][lane];
      #pragma unroll
      for (int j = 1; j < 4; ++j) {
        float4 v = red_s[j][b][lane];
        s.x += v.x; s.y += v.y; s.z += v.z; s.w += v.w;
      }
      *(float4*)(ws + WS_UVPART + (size_t)(y*NB + b)*HID + col4*4) = s;
    }
  }
}

// ------- L7: wo with UVPART self-reduce pre-phase ----------------------------
__global__ __launch_bounds__(256)
void k_wo2(const float* __restrict__ Wo, float* __restrict__ ws) {
  __shared__ float4 red_s[4][NB][64];
  __shared__ float at_s[NB][128];
  const int tid = threadIdx.x;
  const int x = blockIdx.x & 15, y = blockIdx.x >> 4;
  {
    const int b = tid >> 6, q = tid & 63;
    #pragma unroll
    for (int e = 0; e < 2; ++e) {
      int idx = q*2 + e;
      const float* base = ws + WS_UVPART + (size_t)b*HID + y*128 + idx;
      float s = 0.f;
      #pragma unroll
      for (int p = 0; p < NUV; ++p) s += base[(size_t)p*(NB*HID)];
      at_s[b][idx] = s;
    }
  }
  __syncthreads();
  const int lane = tid & 63, ksub = tid >> 6;
  const int col4 = x * 64 + lane;
  const float4* wp = (const float4*)Wo + (size_t)(y*128 + ksub*32) * 1024 + col4;
  float4 acc[NB] = {};
  #pragma unroll 8
  for (int i = 0; i < 32; ++i) {
    float4 w4 = wp[(size_t)i * 1024];
    #pragma unroll
    for (int b = 0; b < NB; ++b)
      fma4(acc[b], at_s[b][ksub*32 + i], w4);
  }
  #pragma unroll
  for (int b = 0; b < NB; ++b) red_s[ksub][b][lane] = acc[b];
  __syncthreads();
  if (ksub == 0) {
    #pragma unroll
    for (int b = 0; b < NB; ++b) {
      float4 s = red_s[0][b][lane];
      #pragma unroll
      for (int j = 1; j < 4; ++j) {
        float4 v = red_s[j][b][lane];
        s.x += v.x; s.y += v.y; s.z += v.z; s.w += v.w;
      }
      *(float4*)(ws + WS_WOPART + (size_t)(y*NB + b)*HID + col4*4) = s;
    }
  }
}

// ---------------- L8: out = sum_p WOPART[p] ----------------------------------
__global__ __launch_bounds__(256)
void k_reduce5(const float* __restrict__ ws, float* __restrict__ out) {
  const int idx = blockIdx.x * 256 + threadIdx.x;
  float4 s = {};
  #pragma unroll 8
  for (int p = 0; p < NWO; ++p) {
    float4 v = *(const float4*)(ws + WS_WOPART + (size_t)p*(NB*HID) + (size_t)idx*4);
    s.x += v.x; s.y += v.y; s.z += v.z; s.w += v.w;
  }
  *(float4*)(out + (size_t)idx*4) = s;
}

extern "C" void kernel_launch(void* const* d_in, const int* in_sizes, int n_in,
                              void* d_out, int out_size, void* d_ws, size_t ws_size,
                              hipStream_t stream) {
  (void)in_sizes; (void)n_in; (void)out_size; (void)ws_size;
  const float* hidden = (const float*)d_in[0];
  const float* mask   = (const float*)d_in[1];
  const float* ckv_c  = (const float*)d_in[2];
  const float* kr_c   = (const float*)d_in[3];
  const float* Wdkv   = (const float*)d_in[4];
  const float* Wuk    = (const float*)d_in[5];
  const float* Wuv    = (const float*)d_in[6];
  const float* Wdq    = (const float*)d_in[7];
  const float* Wuq    = (const float*)d_in[8];
  const float* Wqr    = (const float*)d_in[9];
  const float* Wkr    = (const float*)d_in[10];
  const float* Wo     = (const float*)d_in[11];
  float* out = (float*)d_out;
  float* ws  = (float*)d_ws;
  float* out_ckv = out + NB*HID;
  float* out_kr  = out + NB*HID + (size_t)NB*SK*CKV;

  k_proj1copy<<<9792, 256, 0, stream>>>(hidden, Wdkv, Wdq, Wkr, ws,
                                        (const float4*)ckv_c, (const float4*)kr_c,
                                        (float4*)out_ckv, (float4*)out_kr);
  k_proj2r1<<<585, 256, 0, stream>>>(Wuq, Wqr, ws, out_ckv, out_kr);
  k_absorb_rope<<<260, 256, 0, stream>>>(Wuk, ws);
  k_scores_mfma<<<dim3(129, 4), 256, 0, stream>>>(ws);
  k_pvflash<<<dim3(NPV, 4, 4), 256, 0, stream>>>(mask, ws);
  k_uv2<<<256, 256, 0, stream>>>(Wuv, ws);
  k_wo2<<<512, 256, 0, stream>>>(Wo, ws);
  k_reduce5<<<16, 256, 0, stream>>>(ws, out);
}

// Round 19
// 100.521 us; speedup vs baseline: 1.1986x; 1.0657x over previous
//
#include <hip/hip_runtime.h>
#include <math.h>

#define NB 4
#define HID 4096
#define CKV 512
#define CQ 1536
#define NH 32
#define HD 128
#define RD 64
#define SS 4096
#define SK 4097
#define SKP 4100

#define SCALE_F 0.07216878364870322f  // 1/sqrt(192)

#define NP1 64   // proj1 k-partials
#define NP2 24   // proj2 k-partials
#define NPV 32   // pv key-chunks (128 keys)
#define NUV 16   // uv c-partials
#define NWO 32   // wo k-partials

#define KD   576      // latent 512 + rope 64, contiguous bf16 rows
#define QKB_STR 584   // kv LDS bf16 row stride
#define PBF_STR 4104  // bf16 probs row stride (16B-aligned)
#define TV_STR 40     // pv kvT LDS row stride in u16

typedef __attribute__((ext_vector_type(8))) short short8v;
typedef __attribute__((ext_vector_type(4))) float f32x4;

// workspace offsets (floats). ALL regions disjoint (ws is 256 MB).
enum : int {
  WS_QABS  = 0,
  WS_QROPE = WS_QABS + NB*NH*CKV,
  WS_KROPE = WS_QROPE + NB*NH*RD,
  WS_CKV   = WS_KROPE + NB*RD,
  WS_CQ    = WS_CKV + NB*CKV,
  WS_SCA   = WS_CQ + NB*CQ,            // [NB][NH][SKP] raw scores (f32)
  WS_P1    = WS_SCA + NB*NH*SKP,
  WS_P2    = WS_P1 + NP1*NB*528*4,
  WS_OPART = WS_P2 + NP2*NB*6144,      // [NPV][NB][NH][CKV]
  WS_UVPART= WS_OPART + NPV*NB*NH*CKV,
  WS_WOPART= WS_UVPART + NUV*NB*HID,
  WS_KVBF  = WS_WOPART + NWO*NB*HID,   // bf16 [NB][SK][576]
  WS_QBF   = WS_KVBF + (NB*SK*KD)/2,   // bf16 [NB][NH][576]
  WS_PBF   = WS_QBF + (NB*NH*KD)/2,    // bf16 [NB][NH][PBF_STR] probs
  WS_TOTAL = WS_PBF + (NB*NH*PBF_STR)/2
};

__device__ inline void fma4(float4& a, float s, const float4& v) {
  a.x += s*v.x; a.y += s*v.y; a.z += s*v.z; a.w += s*v.w;
}
__device__ inline float dot4(const float4& a, const float4& b) {
  return a.x*b.x + a.y*b.y + a.z*b.z + a.w*b.w;
}
__device__ inline unsigned short f2bf(float f) {
  union { float f; unsigned int u; } v; v.f = f;
  unsigned int r = v.u + 0x7FFFu + ((v.u >> 16) & 1u);
  return (unsigned short)(r >> 16);
}
__device__ inline ushort4 f2bf4(float4 v) {
  ushort4 r; r.x = f2bf(v.x); r.y = f2bf(v.y); r.z = f2bf(v.z); r.w = f2bf(v.w);
  return r;
}
__device__ inline float bf2f(unsigned short u) {
  union { unsigned int u; float f; } v; v.u = ((unsigned int)u) << 16;
  return v.f;
}

// ------- L1: [bx<576] proj1 -> P1 partials | [else] cache copy + bf16 copy --
__global__ __launch_bounds__(256)
void k_proj1copy(const float* __restrict__ hidden,
                 const float* __restrict__ Wdkv,
                 const float* __restrict__ Wdq,
                 const float* __restrict__ Wkr,
                 float* __restrict__ ws,
                 const float4* __restrict__ src_ckv,
                 const float4* __restrict__ src_kr,
                 float4* __restrict__ dst_ckv,
                 float4* __restrict__ dst_kr) {
  __shared__ float4 red_s[4][NB][64];
  unsigned short* kvbf = (unsigned short*)(ws + WS_KVBF);
  const int bx = blockIdx.x;
  if (bx < 576) {
    const int gx = bx % 9, gy = bx / 9;
    const int lane = threadIdx.x & 63, ksub = threadIdx.x >> 6;
    const int col4 = gx * 64 + lane;
    const int k0 = gy * 64 + ksub * 16;
    const bool valid = col4 < 528;
    float4 acc[NB] = {};
    if (valid) {
      const float* W; int C4, wcol4;
      if (col4 < 128)      { W = Wdkv; C4 = 128; wcol4 = col4; }
      else if (col4 < 512) { W = Wdq;  C4 = 384; wcol4 = col4 - 128; }
      else                 { W = Wkr;  C4 = 16;  wcol4 = col4 - 512; }
      const float4* wp = (const float4*)W + (size_t)k0 * C4 + wcol4;
      #pragma unroll
      for (int i = 0; i < 16; ++i) {
        float4 w4 = wp[(size_t)i * C4];
        #pragma unroll
        for (int b = 0; b < NB; ++b) fma4(acc[b], hidden[b*HID + k0 + i], w4);
      }
    }
    #pragma unroll
    for (int b = 0; b < NB; ++b) red_s[ksub][b][lane] = acc[b];
    __syncthreads();
    if (ksub == 0 && valid) {
      #pragma unroll
      for (int b = 0; b < NB; ++b) {
        float4 s = red_s[0][b][lane];
        #pragma unroll
        for (int j = 1; j < 4; ++j) {
          float4 v = red_s[j][b][lane];
          s.x += v.x; s.y += v.y; s.z += v.z; s.w += v.w;
        }
        *(float4*)(ws + WS_P1 + ((size_t)(gy*NB + b)*528 + col4)*4) = s;
      }
    }
  } else {
    const int bxc = bx - 576;
    if (bxc < 8192) {
      int b = bxc >> 11;
      int idx = (bxc & 2047) * 256 + threadIdx.x;
      float4 v = src_ckv[(size_t)b*(SS*CKV/4) + idx];
      dst_ckv[(size_t)b*(SK*CKV/4) + idx] = v;
      int off = idx * 4;
      int k = off >> 9, c = off & 511;
      *(ushort4*)(kvbf + ((size_t)b*SK + k)*KD + c) = f2bf4(v);
    } else {
      int bx2 = bxc - 8192;
      int b = bx2 >> 8;
      int idx = (bx2 & 255) * 256 + threadIdx.x;
      float4 v = src_kr[(size_t)b*(SS*RD/4) + idx];
      dst_kr[(size_t)b*(SK*RD/4) + idx] = v;
      int off = idx * 4;
      int k = off >> 6, rr = off & 63;
      *(ushort4*)(kvbf + ((size_t)b*SK + k)*KD + 512 + rr) = f2bf4(v);
    }
  }
}

// ------- L2: [bx<576] proj2 (self-reduced act from P1) | [else] reduce1 ------
__global__ __launch_bounds__(256)
void k_proj2r1(const float* __restrict__ Wuq,
               const float* __restrict__ Wqr,
               float* __restrict__ ws,
               float* __restrict__ out_ckv,
               float* __restrict__ out_kr) {
  __shared__ float4 red_s[4][NB][64];
  __shared__ float act_s[NB][64];
  unsigned short* kvbf = (unsigned short*)(ws + WS_KVBF);
  const int bx = blockIdx.x;
  const int tid = threadIdx.x;
  if (bx < 576) {
    const int gx = bx % 24, gy = bx / 24;
    {
      const int b = tid >> 6, i = tid & 63;
      const int k = gy * 64 + i;
      const float* base = ws + WS_P1 + (size_t)b*2112 + 512 + k;
      float s = 0.f;
      #pragma unroll 8
      for (int p = 0; p < NP1; ++p) s += base[(size_t)p*NB*2112];
      act_s[b][i] = s;
    }
    __syncthreads();
    const int lane = tid & 63, ksub = tid >> 6;
    const int col4 = gx * 64 + lane;
    const float* W; int C4, wcol4;
    if (col4 < 1024) { W = Wuq; C4 = 1024; wcol4 = col4; }
    else             { W = Wqr; C4 = 512;  wcol4 = col4 - 1024; }
    const float4* wp = (const float4*)W + (size_t)(gy*64 + ksub*16) * C4 + wcol4;
    float4 acc[NB] = {};
    #pragma unroll
    for (int i = 0; i < 16; ++i) {
      float4 w4 = wp[(size_t)i * C4];
      #pragma unroll
      for (int b = 0; b < NB; ++b) fma4(acc[b], act_s[b][ksub*16 + i], w4);
    }
    #pragma unroll
    for (int b = 0; b < NB; ++b) red_s[ksub][b][lane] = acc[b];
    __syncthreads();
    if (ksub == 0) {
      #pragma unroll
      for (int b = 0; b < NB; ++b) {
        float4 s = red_s[0][b][lane];
        #pragma unroll
        for (int j = 1; j < 4; ++j) {
          float4 v = red_s[j][b][lane];
          s.x += v.x; s.y += v.y; s.z += v.z; s.w += v.w;
        }
        *(float4*)(ws + WS_P2 + (size_t)(gy*NB + b)*6144 + col4*4) = s;
      }
    }
  } else {
    const int w = (bx - 576) * 256 + tid;
    if (w >= 528*NB) return;
    const int b = w / 528, col4 = w % 528;
    float4 s = {};
    #pragma unroll 8
    for (int p = 0; p < NP1; ++p) {
      float4 v = *(const float4*)(ws + WS_P1 + ((size_t)(p*NB + b)*528 + col4)*4);
      s.x += v.x; s.y += v.y; s.z += v.z; s.w += v.w;
    }
    if (col4 < 128) {
      *(float4*)(ws + WS_CKV + b*CKV + col4*4) = s;
      *(float4*)(out_ckv + (size_t)b*SK*CKV + (size_t)SS*CKV + col4*4) = s;
      *(ushort4*)(kvbf + ((size_t)b*SK + SS)*KD + col4*4) = f2bf4(s);
    } else if (col4 < 512) {
      *(float4*)(ws + WS_CQ + b*CQ + (col4 - 128)*4) = s;
    } else {
      const int c0 = (col4 - 512) * 4;
      const double LN1E4 = 9.210340371976184;
      int i0 = c0 >> 1;
      double a0 = 4096.0 * exp(-(double)i0 / 32.0 * LN1E4);
      double a1 = 4096.0 * exp(-(double)(i0 + 1) / 32.0 * LN1E4);
      float c0f = (float)cos(a0), s0f = (float)sin(a0);
      float c1f = (float)cos(a1), s1f = (float)sin(a1);
      float4 o;
      o.x = s.x*c0f - s.y*s0f;  o.y = s.x*s0f + s.y*c0f;
      o.z = s.z*c1f - s.w*s1f;  o.w = s.z*s1f + s.w*c1f;
      *(float4*)(ws + WS_KROPE + b*RD + c0) = o;
      *(float4*)(out_kr + (size_t)b*SK*RD + (size_t)SS*RD + c0) = o;
      *(ushort4*)(kvbf + ((size_t)b*SK + SS)*KD + 512 + c0) = f2bf4(o);
    }
  }
}

// -------- L3: q_abs = q_C @ W_UK^T (×SCALE) + bf16 q; q_R RoPE ---------------
__global__ __launch_bounds__(256)
void k_absorb_rope(const float* __restrict__ Wuk,
                   float* __restrict__ ws) {
  unsigned short* qbf = (unsigned short*)(ws + WS_QBF);
  const int bid = blockIdx.x, tid = threadIdx.x;
  if (bid < 256) {
    const int h = bid >> 3, cq = bid & 7;
    __shared__ float qc_s[NB][HD];
    __shared__ float part_s[NB][256];
    for (int e = tid; e < NB*HD; e += 256) {
      int b = e >> 7, d = e & 127;
      float v = 0.f;
      #pragma unroll
      for (int p = 0; p < NP2; ++p)
        v += ws[WS_P2 + (size_t)(p*NB + b)*6144 + h*HD + d];
      qc_s[b][d] = v;
    }
    __syncthreads();
    const int c = cq*64 + (tid & 63);
    const int dg = tid >> 6;
    const float4* wrow = (const float4*)(Wuk + (size_t)c*(NH*HD) + h*HD + dg*32);
    float acc[NB] = {0,0,0,0};
    #pragma unroll
    for (int d4 = 0; d4 < 8; ++d4) {
      float4 w4 = wrow[d4];
      #pragma unroll
      for (int b = 0; b < NB; ++b)
        acc[b] += dot4(w4, *(const float4*)&qc_s[b][dg*32 + d4*4]);
    }
    #pragma unroll
    for (int b = 0; b < NB; ++b) part_s[b][tid] = acc[b];
    __syncthreads();
    if (tid < 64) {
      #pragma unroll
      for (int b = 0; b < NB; ++b) {
        float v = (part_s[b][tid] + part_s[b][tid+64] + part_s[b][tid+128] + part_s[b][tid+192]) * SCALE_F;
        ws[WS_QABS + (size_t)(b*NH + h)*CKV + cq*64 + tid] = v;
        qbf[(size_t)(b*NH + h)*KD + cq*64 + tid] = f2bf(v);
      }
    }
  } else {
    const int b = bid - 256;
    const double LN1E4 = 9.210340371976184;
    for (int pid = tid; pid < NH*32; pid += 256) {
      int h = pid >> 5, i = pid & 31;
      float x1 = 0.f, x2 = 0.f;
      #pragma unroll
      for (int p = 0; p < NP2; ++p) {
        const float* base = ws + WS_P2 + (size_t)(p*NB + b)*6144 + 4096 + h*RD + 2*i;
        x1 += base[0]; x2 += base[1];
      }
      double ang = 4096.0 * exp(-(double)i / 32.0 * LN1E4);
      float cs = (float)cos(ang), sn = (float)sin(ang);
      float o0 = (x1*cs - x2*sn) * SCALE_F;
      float o1 = (x1*sn + x2*cs) * SCALE_F;
      ws[WS_QROPE + (b*NH + h)*RD + 2*i]     = o0;
      ws[WS_QROPE + (b*NH + h)*RD + 2*i + 1] = o1;
      qbf[(size_t)(b*NH + h)*KD + 512 + 2*i]     = f2bf(o0);
      qbf[(size_t)(b*NH + h)*KD + 512 + 2*i + 1] = f2bf(o1);
    }
  }
}

// ---------------- L4: scores via MFMA bf16 — q from global (R16 proven) ------
__global__ __launch_bounds__(256)
void k_scores_mfma(float* __restrict__ ws) {
  __shared__ unsigned short kv_s[32 * QKB_STR];
  const unsigned short* kvbf = (const unsigned short*)(ws + WS_KVBF);
  const unsigned short* qbf  = (const unsigned short*)(ws + WS_QBF);
  const int tid = threadIdx.x;
  const int b  = blockIdx.y;
  const int k0 = blockIdx.x * 32;
  {
    const int r = tid >> 3, u0 = tid & 7;
    const int k = k0 + r;
    const unsigned short* ksrc = (k <= SS) ? (kvbf + ((size_t)b*SK + k)*KD) : nullptr;
    #pragma unroll
    for (int j = 0; j < 9; ++j) {
      int u = (u0 + 8*j) * 8;
      uint4 kvv = {0u, 0u, 0u, 0u};
      if (ksrc) kvv = *(const uint4*)(ksrc + u);
      *(uint4*)&kv_s[r*QKB_STR + u] = kvv;
    }
  }
  __syncthreads();
  const int wid = tid >> 6, lane = tid & 63;
  const int m0 = (wid & 1) * 16;
  const int n0 = (wid >> 1) * 16;
  const int l15 = lane & 15, lq = lane >> 4;
  const unsigned short* arow = qbf + (size_t)(b*NH + m0 + l15)*KD + lq*8;
  const unsigned short* brow = &kv_s[(n0 + l15)*QKB_STR + lq*8];
  f32x4 acc = {0.f, 0.f, 0.f, 0.f};
  #pragma unroll
  for (int ks = 0; ks < 18; ++ks) {
    short8v a = *(const short8v*)(arow + ks*32);
    short8v bb = *(const short8v*)(brow + ks*32);
    acc = __builtin_amdgcn_mfma_f32_16x16x32_bf16(a, bb, acc, 0, 0, 0);
  }
  const int key = k0 + n0 + l15;
  if (key <= SS) {
    #pragma unroll
    for (int r = 0; r < 4; ++r) {
      int h = m0 + lq*4 + r;
      ws[WS_SCA + (size_t)(b*NH + h)*SKP + key] = acc[r];
    }
  }
}

// ---------------- L5: softmax(SCA + mask) -> bf16 probs (1024 threads) -------
__global__ __launch_bounds__(1024)
void k_softmax(const float* __restrict__ mask, float* __restrict__ ws) {
  __shared__ float red[1024];
  unsigned short* pbf = (unsigned short*)(ws + WS_PBF);
  const int tid = threadIdx.x;
  const int b = blockIdx.x >> 5;
  const float* sa = ws + WS_SCA + (size_t)blockIdx.x * SKP;
  unsigned short* prow = pbf + (size_t)blockIdx.x * PBF_STR;
  const float* mrow = mask + (size_t)b * SK;
  float v[5];
  float m = -INFINITY;
  #pragma unroll
  for (int r = 0; r < 5; ++r) {
    int k = tid + r*1024;
    v[r] = (k < SK) ? (sa[k] + mrow[k] * (-1e9f)) : -INFINITY;
    m = fmaxf(m, v[r]);
  }
  red[tid] = m; __syncthreads();
  for (int st = 512; st > 0; st >>= 1) {
    if (tid < st) red[tid] = fmaxf(red[tid], red[tid+st]);
    __syncthreads();
  }
  m = red[0]; __syncthreads();
  float e[5];
  float l = 0.f;
  #pragma unroll
  for (int r = 0; r < 5; ++r) {
    int k = tid + r*1024;
    e[r] = (k < SK) ? __expf(v[r] - m) : 0.f;
    l += e[r];
  }
  red[tid] = l; __syncthreads();
  for (int st = 512; st > 0; st >>= 1) {
    if (tid < st) red[tid] += red[tid+st];
    __syncthreads();
  }
  float inv = 1.f / red[0];
  #pragma unroll
  for (int r = 0; r < 5; ++r) {
    int k = tid + r*1024;
    if (k < SK) prow[k] = f2bf(e[r] * inv);
  }
}

// ---------------- L6: pv via MFMA — in-LDS kv transpose (R16 proven) ---------
__global__ __launch_bounds__(256)
void k_pv_mfma(float* __restrict__ ws) {
  __shared__ unsigned short kvT_s[128 * TV_STR];
  const unsigned short* kvbf = (const unsigned short*)(ws + WS_KVBF);
  const unsigned short* pbf  = (const unsigned short*)(ws + WS_PBF);
  const int tid = threadIdx.x;
  const int b  = blockIdx.z;
  const int c0 = blockIdx.y * 128;
  const int k0 = blockIdx.x * 128;
  const int wid = tid >> 6, lane = tid & 63;
  const int l15 = lane & 15, lq = lane >> 4;
  const int m0 = (wid & 1) * 16;
  const int nq = (wid >> 1) * 4;
  f32x4 acc[4] = {{0,0,0,0},{0,0,0,0},{0,0,0,0},{0,0,0,0}};
  const int kk_st = tid & 31, cgrp = tid >> 5;
  #pragma unroll
  for (int sc = 0; sc < 4; ++sc) {
    const int ks0 = k0 + sc*32;
    {
      const unsigned short* src = kvbf + ((size_t)b*SK + ks0 + kk_st)*KD + c0 + cgrp*16;
      #pragma unroll
      for (int half = 0; half < 2; ++half) {
        ushort4 v0 = *(const ushort4*)(src + half*8);
        ushort4 v1 = *(const ushort4*)(src + half*8 + 4);
        int cb = cgrp*16 + half*8;
        kvT_s[(cb+0)*TV_STR + kk_st] = v0.x;
        kvT_s[(cb+1)*TV_STR + kk_st] = v0.y;
        kvT_s[(cb+2)*TV_STR + kk_st] = v0.z;
        kvT_s[(cb+3)*TV_STR + kk_st] = v0.w;
        kvT_s[(cb+4)*TV_STR + kk_st] = v1.x;
        kvT_s[(cb+5)*TV_STR + kk_st] = v1.y;
        kvT_s[(cb+6)*TV_STR + kk_st] = v1.z;
        kvT_s[(cb+7)*TV_STR + kk_st] = v1.w;
      }
    }
    __syncthreads();
    short8v a = *(const short8v*)(pbf + (size_t)(b*NH + m0 + l15)*PBF_STR + ks0 + lq*8);
    #pragma unroll
    for (int nt = 0; nt < 4; ++nt) {
      const unsigned short* brow = &kvT_s[((nq + nt)*16 + l15)*TV_STR + lq*8];
      short8v bb = *(const short8v*)(brow);
      acc[nt] = __builtin_amdgcn_mfma_f32_16x16x32_bf16(a, bb, acc[nt], 0, 0, 0);
    }
    __syncthreads();
  }
  #pragma unroll
  for (int nt = 0; nt < 4; ++nt) {
    const int c = c0 + (nq + nt)*16 + l15;
    #pragma unroll
    for (int r = 0; r < 4; ++r) {
      int h = m0 + lq*4 + r;
      ws[WS_OPART + (((size_t)blockIdx.x*NB + b)*NH + h)*CKV + c] = acc[nt][r];
    }
  }
}

// ------- L7: uv with OPART self-reduce pre-phase + tail-key (SS) term --------
__global__ __launch_bounds__(256)
void k_uv2(const float* __restrict__ Wuv, float* __restrict__ ws) {
  __shared__ float4 red_s[4][NB][64];
  __shared__ float ol_s[NB][2][32];
  const unsigned short* kvbf = (const unsigned short*)(ws + WS_KVBF);
  const unsigned short* pbf  = (const unsigned short*)(ws + WS_PBF);
  const int tid = threadIdx.x;
  const int x = blockIdx.x & 15, y = blockIdx.x >> 4;
  {
    const int b = tid >> 6, hh = (tid >> 5) & 1, ci = tid & 31;
    const int h = 2*x + hh, c = y*32 + ci;
    const float* base = ws + WS_OPART + ((size_t)b*NH + h)*CKV + c;
    float s = 0.f;
    #pragma unroll 8
    for (int p = 0; p < NPV; ++p) s += base[(size_t)p*(NB*NH*CKV)];
    s += bf2f(pbf[(size_t)(b*NH + h)*PBF_STR + SS]) *
         bf2f(kvbf[((size_t)b*SK + SS)*KD + c]);
    ol_s[b][hh][ci] = s;
  }
  __syncthreads();
  const int lane = tid & 63, csub = tid >> 6;
  const int col4 = x * 64 + lane;
  const int hh = (col4 >> 5) & 1;
  const float4* wp = (const float4*)Wuv + (size_t)(y*32 + csub*8) * 1024 + col4;
  float4 acc[NB] = {};
  #pragma unroll
  for (int i = 0; i < 8; ++i) {
    float4 w4 = wp[(size_t)i * 1024];
    #pragma unroll
    for (int b = 0; b < NB; ++b)
      fma4(acc[b], ol_s[b][hh][csub*8 + i], w4);
  }
  #pragma unroll
  for (int b = 0; b < NB; ++b) red_s[csub][b][lane] = acc[b];
  __syncthreads();
  if (csub == 0) {
    #pragma unroll
    for (int b = 0; b < NB; ++b) {
      float4 s = red_s[0][b][lane];
      #pragma unroll
      for (int j = 1; j < 4; ++j) {
        float4 v = red_s[j][b][lane];
        s.x += v.x; s.y += v.y; s.z += v.z; s.w += v.w;
      }
      *(float4*)(ws + WS_UVPART + (size_t)(y*NB + b)*HID + col4*4) = s;
    }
  }
}

// ------- L8: wo with UVPART self-reduce pre-phase ----------------------------
__global__ __launch_bounds__(256)
void k_wo2(const float* __restrict__ Wo, float* __restrict__ ws) {
  __shared__ float4 red_s[4][NB][64];
  __shared__ float at_s[NB][128];
  const int tid = threadIdx.x;
  const int x = blockIdx.x & 15, y = blockIdx.x >> 4;
  {
    const int b = tid >> 6, q = tid & 63;
    #pragma unroll
    for (int e = 0; e < 2; ++e) {
      int idx = q*2 + e;
      const float* base = ws + WS_UVPART + (size_t)b*HID + y*128 + idx;
      float s = 0.f;
      #pragma unroll
      for (int p = 0; p < NUV; ++p) s += base[(size_t)p*(NB*HID)];
      at_s[b][idx] = s;
    }
  }
  __syncthreads();
  const int lane = tid & 63, ksub = tid >> 6;
  const int col4 = x * 64 + lane;
  const float4* wp = (const float4*)Wo + (size_t)(y*128 + ksub*32) * 1024 + col4;
  float4 acc[NB] = {};
  #pragma unroll 8
  for (int i = 0; i < 32; ++i) {
    float4 w4 = wp[(size_t)i * 1024];
    #pragma unroll
    for (int b = 0; b < NB; ++b)
      fma4(acc[b], at_s[b][ksub*32 + i], w4);
  }
  #pragma unroll
  for (int b = 0; b < NB; ++b) red_s[ksub][b][lane] = acc[b];
  __syncthreads();
  if (ksub == 0) {
    #pragma unroll
    for (int b = 0; b < NB; ++b) {
      float4 s = red_s[0][b][lane];
      #pragma unroll
      for (int j = 1; j < 4; ++j) {
        float4 v = red_s[j][b][lane];
        s.x += v.x; s.y += v.y; s.z += v.z; s.w += v.w;
      }
      *(float4*)(ws + WS_WOPART + (size_t)(y*NB + b)*HID + col4*4) = s;
    }
  }
}

// ---------------- L9: out = sum_p WOPART[p] ----------------------------------
__global__ __launch_bounds__(256)
void k_reduce5(const float* __restrict__ ws, float* __restrict__ out) {
  const int idx = blockIdx.x * 256 + threadIdx.x;
  float4 s = {};
  #pragma unroll 8
  for (int p = 0; p < NWO; ++p) {
    float4 v = *(const float4*)(ws + WS_WOPART + (size_t)p*(NB*HID) + (size_t)idx*4);
    s.x += v.x; s.y += v.y; s.z += v.z; s.w += v.w;
  }
  *(float4*)(out + (size_t)idx*4) = s;
}

extern "C" void kernel_launch(void* const* d_in, const int* in_sizes, int n_in,
                              void* d_out, int out_size, void* d_ws, size_t ws_size,
                              hipStream_t stream) {
  (void)in_sizes; (void)n_in; (void)out_size; (void)ws_size;
  const float* hidden = (const float*)d_in[0];
  const float* mask   = (const float*)d_in[1];
  const float* ckv_c  = (const float*)d_in[2];
  const float* kr_c   = (const float*)d_in[3];
  const float* Wdkv   = (const float*)d_in[4];
  const float* Wuk    = (const float*)d_in[5];
  const float* Wuv    = (const float*)d_in[6];
  const float* Wdq    = (const float*)d_in[7];
  const float* Wuq    = (const float*)d_in[8];
  const float* Wqr    = (const float*)d_in[9];
  const float* Wkr    = (const float*)d_in[10];
  const float* Wo     = (const float*)d_in[11];
  float* out = (float*)d_out;
  float* ws  = (float*)d_ws;
  float* out_ckv = out + NB*HID;
  float* out_kr  = out + NB*HID + (size_t)NB*SK*CKV;

  k_proj1copy<<<9792, 256, 0, stream>>>(hidden, Wdkv, Wdq, Wkr, ws,
                                        (const float4*)ckv_c, (const float4*)kr_c,
                                        (float4*)out_ckv, (float4*)out_kr);
  k_proj2r1<<<585, 256, 0, stream>>>(Wuq, Wqr, ws, out_ckv, out_kr);
  k_absorb_rope<<<260, 256, 0, stream>>>(Wuk, ws);
  k_scores_mfma<<<dim3(129, 4), 256, 0, stream>>>(ws);
  k_softmax<<<NB*NH, 1024, 0, stream>>>(mask, ws);
  k_pv_mfma<<<dim3(NPV, 4, 4), 256, 0, stream>>>(ws);
  k_uv2<<<256, 256, 0, stream>>>(Wuv, ws);
  k_wo2<<<512, 256, 0, stream>>>(Wo, ws);
  k_reduce5<<<16, 256, 0, stream>>>(ws, out);
}